// Round 2
// baseline (31.827 us; speedup 1.0000x reference)
//
#include <hip/hip_runtime.h>
#include <hip/hip_bf16.h>

// GATv2 dense complete-graph, B=32, W=128 (in-feat), F=64 (nodes), H=2, D=128.
// K1: el/er projection (batched GEMM on fp32 VALU; no fp32 MFMA on CDNA4).
// K2: per (b, h, i-tile of 16): scores + softmax + aggregate + atomic head-mean.

constexpr int kB = 32, kW = 128, kF = 64, kH = 2, kD = 128, kHD = 256;
constexpr float kNeg = 0.2f;

__device__ __forceinline__ float lrelu(float v) { return fmaxf(v, kNeg * v); }

// ---------------- K1: projection ----------------
// grid = B*8 (8 column-slices of 32), block = 256.
// thread: one column c (of 256), 8 node-rows; computes el and er together.
__global__ __launch_bounds__(256) void gat_proj(
    const float* __restrict__ x, const float* __restrict__ Wl,
    const float* __restrict__ Wr, float* __restrict__ elw,
    float* __restrict__ erw) {
  __shared__ float xw[kW][kF + 4];  // stride 68 words: banks (4w+n)%32, 16B-aligned rows
  const int b = blockIdx.x >> 3;
  const int c0 = (blockIdx.x & 7) << 5;
  const int t = threadIdx.x;

  const float* xb = x + b * (kW * kF);
#pragma unroll
  for (int k = 0; k < 32; ++k) {
    const int idx = t + (k << 8);
    xw[idx >> 6][idx & 63] = xb[idx];  // xn[n][w] transpose: xw[w][n] = x[b][w][n]
  }
  __syncthreads();

  const int c = c0 + (t & 31);
  const int n0 = (t >> 5) << 3;  // 8 rows per thread
  float accl[8] = {0.f, 0.f, 0.f, 0.f, 0.f, 0.f, 0.f, 0.f};
  float accr[8] = {0.f, 0.f, 0.f, 0.f, 0.f, 0.f, 0.f, 0.f};

#pragma unroll 4
  for (int w = 0; w < kW; ++w) {
    const float wl = Wl[w * kHD + c];
    const float wr = Wr[w * kHD + c];
    const float4 xa = *(const float4*)&xw[w][n0];
    const float4 xc = *(const float4*)&xw[w][n0 + 4];
    accl[0] = fmaf(xa.x, wl, accl[0]); accr[0] = fmaf(xa.x, wr, accr[0]);
    accl[1] = fmaf(xa.y, wl, accl[1]); accr[1] = fmaf(xa.y, wr, accr[1]);
    accl[2] = fmaf(xa.z, wl, accl[2]); accr[2] = fmaf(xa.z, wr, accr[2]);
    accl[3] = fmaf(xa.w, wl, accl[3]); accr[3] = fmaf(xa.w, wr, accr[3]);
    accl[4] = fmaf(xc.x, wl, accl[4]); accr[4] = fmaf(xc.x, wr, accr[4]);
    accl[5] = fmaf(xc.y, wl, accl[5]); accr[5] = fmaf(xc.y, wr, accr[5]);
    accl[6] = fmaf(xc.z, wl, accl[6]); accr[6] = fmaf(xc.z, wr, accr[6]);
    accl[7] = fmaf(xc.w, wl, accl[7]); accr[7] = fmaf(xc.w, wr, accr[7]);
  }

  const int base = (b * kF + n0) * kHD + c;
#pragma unroll
  for (int k = 0; k < 8; ++k) {
    elw[base + k * kHD] = accl[k];
    erw[base + k * kHD] = accr[k];
  }
}

// ---------------- K2: attention ----------------
// grid = B*H*4 (i-tiles of 16), block = 256.
__global__ __launch_bounds__(256) void gat_attn(
    const float* __restrict__ elw, const float* __restrict__ erw,
    const float* __restrict__ attn_a, const float* __restrict__ bias,
    float* __restrict__ out) {
  __shared__ float el[kF][kD + 4];   // stride 132
  __shared__ float er[16][kD + 4];
  __shared__ float av[kD];
  __shared__ float sT[kF][20];       // scores transposed [j][i], stride 20 (16B-aligned)

  const int b = blockIdx.x >> 3;
  const int h = (blockIdx.x >> 2) & 1;
  const int i0 = (blockIdx.x & 3) << 4;
  const int t = threadIdx.x;

  // stage el (all 64 src rows, this head's 128 dims) and er (16 dst rows)
  {
    const int dv = (t & 31) << 2;
    const int nr = t >> 5;
    const float* elb = elw + b * kF * kHD + h * kD;
#pragma unroll
    for (int k = 0; k < 8; ++k) {
      const int n = nr + (k << 3);
      *(float4*)&el[n][dv] = *(const float4*)&elb[n * kHD + dv];
    }
    const float* erb = erw + (b * kF + i0) * kHD + h * kD;
#pragma unroll
    for (int k = 0; k < 2; ++k) {
      const int r = nr + (k << 3);
      *(float4*)&er[r][dv] = *(const float4*)&erb[r * kHD + dv];
    }
  }
  if (t < kD) av[t] = attn_a[h * kD + t];
  __syncthreads();

  // scores: thread (i = t>>4 in [0,16), jq = t&15), handles j = jq + 16*jj
  {
    const int i = t >> 4, jq = t & 15;
    float e0 = 0.f, e1 = 0.f, e2 = 0.f, e3 = 0.f;
#pragma unroll
    for (int dv = 0; dv < kD; dv += 4) {
      const float4 erv = *(const float4*)&er[i][dv];
      const float4 a4 = *(const float4*)&av[dv];
      const float4 p0 = *(const float4*)&el[jq][dv];
      const float4 p1 = *(const float4*)&el[jq + 16][dv];
      const float4 p2 = *(const float4*)&el[jq + 32][dv];
      const float4 p3 = *(const float4*)&el[jq + 48][dv];
      e0 = fmaf(lrelu(p0.x + erv.x), a4.x, e0);
      e0 = fmaf(lrelu(p0.y + erv.y), a4.y, e0);
      e0 = fmaf(lrelu(p0.z + erv.z), a4.z, e0);
      e0 = fmaf(lrelu(p0.w + erv.w), a4.w, e0);
      e1 = fmaf(lrelu(p1.x + erv.x), a4.x, e1);
      e1 = fmaf(lrelu(p1.y + erv.y), a4.y, e1);
      e1 = fmaf(lrelu(p1.z + erv.z), a4.z, e1);
      e1 = fmaf(lrelu(p1.w + erv.w), a4.w, e1);
      e2 = fmaf(lrelu(p2.x + erv.x), a4.x, e2);
      e2 = fmaf(lrelu(p2.y + erv.y), a4.y, e2);
      e2 = fmaf(lrelu(p2.z + erv.z), a4.z, e2);
      e2 = fmaf(lrelu(p2.w + erv.w), a4.w, e2);
      e3 = fmaf(lrelu(p3.x + erv.x), a4.x, e3);
      e3 = fmaf(lrelu(p3.y + erv.y), a4.y, e3);
      e3 = fmaf(lrelu(p3.z + erv.z), a4.z, e3);
      e3 = fmaf(lrelu(p3.w + erv.w), a4.w, e3);
    }
    sT[jq][i] = e0;
    sT[jq + 16][i] = e1;
    sT[jq + 32][i] = e2;
    sT[jq + 48][i] = e3;
  }
  __syncthreads();

  // softmax over j (64) per dst i: 16 lanes per i, 4 j's each, shuffle-reduce
  {
    const int i = t >> 4, q = t & 15;
    const float v0 = sT[q][i], v1 = sT[q + 16][i], v2 = sT[q + 32][i],
                v3 = sT[q + 48][i];
    float m = fmaxf(fmaxf(v0, v1), fmaxf(v2, v3));
#pragma unroll
    for (int off = 1; off < 16; off <<= 1) m = fmaxf(m, __shfl_xor(m, off));
    float s = __expf(v0 - m) + __expf(v1 - m) + __expf(v2 - m) + __expf(v3 - m);
#pragma unroll
    for (int off = 1; off < 16; off <<= 1) s += __shfl_xor(s, off);
    const float inv = 1.f / s;
    sT[q][i] = __expf(v0 - m) * inv;
    sT[q + 16][i] = __expf(v1 - m) * inv;
    sT[q + 32][i] = __expf(v2 - m) * inv;
    sT[q + 48][i] = __expf(v3 - m) * inv;
  }
  __syncthreads();

  // aggregate: thread (ii = t&15 dst-local, dh = (t>>4)*8 d-range of 8)
  {
    const int ii = t & 15;
    const int dh = (t >> 4) << 3;
    float acc[8] = {0.f, 0.f, 0.f, 0.f, 0.f, 0.f, 0.f, 0.f};
#pragma unroll 4
    for (int j = 0; j < kF; ++j) {
      const float al = sT[j][ii];
      const float4 e0 = *(const float4*)&el[j][dh];
      const float4 e1 = *(const float4*)&el[j][dh + 4];
      acc[0] = fmaf(al, e0.x, acc[0]);
      acc[1] = fmaf(al, e0.y, acc[1]);
      acc[2] = fmaf(al, e0.z, acc[2]);
      acc[3] = fmaf(al, e0.w, acc[3]);
      acc[4] = fmaf(al, e1.x, acc[4]);
      acc[5] = fmaf(al, e1.y, acc[5]);
      acc[6] = fmaf(al, e1.z, acc[6]);
      acc[7] = fmaf(al, e1.w, acc[7]);
    }
    float* ob = out + b * kD * kF + i0 + ii;
#pragma unroll
    for (int k = 0; k < 8; ++k) {
      const int d = dh + k;
      atomicAdd(&ob[d * kF], 0.5f * (acc[k] + bias[h * kD + d]));
    }
  }
}

extern "C" void kernel_launch(void* const* d_in, const int* in_sizes, int n_in,
                              void* d_out, int out_size, void* d_ws,
                              size_t ws_size, hipStream_t stream) {
  (void)in_sizes; (void)n_in; (void)ws_size;
  const float* x = (const float*)d_in[0];
  const float* Wl = (const float*)d_in[1];
  const float* Wr = (const float*)d_in[2];
  const float* attn_a = (const float*)d_in[3];
  const float* bias = (const float*)d_in[4];
  float* out = (float*)d_out;

  float* elw = (float*)d_ws;                       // [B][64][256]
  float* erw = elw + (size_t)kB * kF * kHD;        // [B][64][256]

  hipMemsetAsync(d_out, 0, (size_t)out_size * sizeof(float), stream);
  gat_proj<<<dim3(kB * 8), dim3(256), 0, stream>>>(x, Wl, Wr, elw, erw);
  gat_attn<<<dim3(kB * kH * 4), dim3(256), 0, stream>>>(elw, erw, attn_a, bias,
                                                        out);
}

// Round 3
// 25.876 us; speedup vs baseline: 1.2300x; 1.2300x over previous
//
#include <hip/hip_runtime.h>
#include <hip/hip_bf16.h>

// GATv2 dense complete-graph, B=32, W=128 (in-feat), F=64 (nodes), H=2, D=128.
// K1: el/er projection (batched GEMM on fp32 VALU; no fp32 MFMA on CDNA4).
// K2: per (b, i-tile of 8): BOTH heads -> scores + softmax + aggregate + mean,
//     each output written exactly once (no memset, no atomics).

constexpr int kB = 32, kW = 128, kF = 64, kH = 2, kD = 128, kHD = 256;
constexpr float kNeg = 0.2f;

__device__ __forceinline__ float lrelu(float v) { return fmaxf(v, kNeg * v); }

// ---------------- K1: projection ----------------
// grid = B*8 (8 column-slices of 32), block = 512.
// thread: one column c (of 256), 4 node-rows; computes el and er together.
__global__ __launch_bounds__(512) void gat_proj(
    const float* __restrict__ x, const float* __restrict__ Wl,
    const float* __restrict__ Wr, float* __restrict__ elw,
    float* __restrict__ erw) {
  __shared__ float xw[kW][kF + 4];   // stride 68 words
  __shared__ float wls[kW][32];      // Wl column-slice
  __shared__ float wrs[kW][32];      // Wr column-slice
  const int b = blockIdx.x >> 3;
  const int c0 = (blockIdx.x & 7) << 5;
  const int t = threadIdx.x;

  const float* xb = x + b * (kW * kF);
#pragma unroll
  for (int k = 0; k < 16; ++k) {
    const int idx = t + (k << 9);
    xw[idx >> 6][idx & 63] = xb[idx];  // xw[w][n] = x[b][w][n]
  }
  // stage W slices: 1024 float4 slots each
#pragma unroll
  for (int k = 0; k < 2; ++k) {
    const int s = t + (k << 9);          // 0..1023
    const int w = s >> 3;
    const int cc = (s & 7) << 2;
    *(float4*)&wls[w][cc] = *(const float4*)&Wl[w * kHD + c0 + cc];
    *(float4*)&wrs[w][cc] = *(const float4*)&Wr[w * kHD + c0 + cc];
  }
  __syncthreads();

  const int cl = t & 31;
  const int c = c0 + cl;
  const int n0 = (t >> 5) << 2;  // 4 rows per thread
  float accl[4] = {0.f, 0.f, 0.f, 0.f};
  float accr[4] = {0.f, 0.f, 0.f, 0.f};

#pragma unroll 4
  for (int w = 0; w < kW; ++w) {
    const float wl = wls[w][cl];
    const float wr = wrs[w][cl];
    const float4 xa = *(const float4*)&xw[w][n0];
    accl[0] = fmaf(xa.x, wl, accl[0]); accr[0] = fmaf(xa.x, wr, accr[0]);
    accl[1] = fmaf(xa.y, wl, accl[1]); accr[1] = fmaf(xa.y, wr, accr[1]);
    accl[2] = fmaf(xa.z, wl, accl[2]); accr[2] = fmaf(xa.z, wr, accr[2]);
    accl[3] = fmaf(xa.w, wl, accl[3]); accr[3] = fmaf(xa.w, wr, accr[3]);
  }

  const int base = (b * kF + n0) * kHD + c;
#pragma unroll
  for (int k = 0; k < 4; ++k) {
    elw[base + k * kHD] = accl[k];
    erw[base + k * kHD] = accr[k];
  }
}

// ---------------- K2: attention (both heads per block) ----------------
// grid = B*8 (i-tiles of 8), block = 512.
__global__ __launch_bounds__(512) void gat_attn(
    const float* __restrict__ elw, const float* __restrict__ erw,
    const float* __restrict__ attn_a, const float* __restrict__ bias,
    float* __restrict__ out) {
  __shared__ float el[kH][kF][kD + 4];   // 67.6 KB, stride 132
  __shared__ float er[kH][8][kD + 4];    //  8.4 KB
  __shared__ float av[kH][kD];
  __shared__ float sT[kH][kF][13];       // scores [h][j][i], odd stride -> no conflicts

  const int b = blockIdx.x >> 3;
  const int i0 = (blockIdx.x & 7) << 3;
  const int t = threadIdx.x;

  // ---- stage: el (both heads, all 64 src rows), er (8 dst rows), attn_a ----
  {
    const float* elb = elw + b * (kF * kHD);
#pragma unroll
    for (int k = 0; k < 8; ++k) {
      const int s = t + (k << 9);        // 0..4095 float4 slots
      const int h = s >> 11;
      const int n = (s >> 5) & 63;
      const int dv = (s & 31) << 2;
      *(float4*)&el[h][n][dv] = *(const float4*)&elb[n * kHD + h * kD + dv];
    }
    const float* erb = erw + (b * kF + i0) * kHD;
    {
      const int h = t >> 8;
      const int r = (t >> 5) & 7;
      const int dv = (t & 31) << 2;
      *(float4*)&er[h][r][dv] = *(const float4*)&erb[r * kHD + h * kD + dv];
    }
    if (t < kH * kD) av[t >> 7][t & 127] = attn_a[t];
  }
  __syncthreads();

  // ---- scores: thread (q=t&15, i, h, jhalf) handles j = q+16*jj, 2 j's ----
  {
    const int q = t & 15;
    const int i = (t >> 4) & 7;
    const int h = (t >> 7) & 1;
    const int j0 = q + ((t >> 8) << 5);  // q or q+32
    const int j1 = j0 + 16;
    float e0 = 0.f, e1 = 0.f;
#pragma unroll
    for (int dv = 0; dv < kD; dv += 4) {
      const float4 rv = *(const float4*)&er[h][i][dv];
      const float4 a4 = *(const float4*)&av[h][dv];
      const float4 p0 = *(const float4*)&el[h][j0][dv];
      const float4 p1 = *(const float4*)&el[h][j1][dv];
      e0 = fmaf(lrelu(p0.x + rv.x), a4.x, e0);
      e0 = fmaf(lrelu(p0.y + rv.y), a4.y, e0);
      e0 = fmaf(lrelu(p0.z + rv.z), a4.z, e0);
      e0 = fmaf(lrelu(p0.w + rv.w), a4.w, e0);
      e1 = fmaf(lrelu(p1.x + rv.x), a4.x, e1);
      e1 = fmaf(lrelu(p1.y + rv.y), a4.y, e1);
      e1 = fmaf(lrelu(p1.z + rv.z), a4.z, e1);
      e1 = fmaf(lrelu(p1.w + rv.w), a4.w, e1);
    }
    sT[h][j0][i] = e0;
    sT[h][j1][i] = e1;
  }
  __syncthreads();

  // ---- softmax over j (64) per (h,i): 32 lanes per group, 2 j's each ----
  {
    const int q = t & 31;
    const int g = t >> 5;        // 16 groups = (h,i)
    const int i = g & 7;
    const int h = g >> 3;
    const float v0 = sT[h][q][i];
    const float v1 = sT[h][q + 32][i];
    float m = fmaxf(v0, v1);
#pragma unroll
    for (int off = 1; off < 32; off <<= 1) m = fmaxf(m, __shfl_xor(m, off));
    const float x0 = __expf(v0 - m);
    const float x1 = __expf(v1 - m);
    float s = x0 + x1;
#pragma unroll
    for (int off = 1; off < 32; off <<= 1) s += __shfl_xor(s, off);
    const float inv = 1.f / s;
    sT[h][q][i] = x0 * inv;
    sT[h][q + 32][i] = x1 * inv;
  }
  __syncthreads();

  // ---- aggregate + head-mean + bias, direct store (no atomics) ----
  {
    const int i = t & 7;
    const int dh = (t >> 3) << 1;   // 2 d's per thread
    float a00 = 0.f, a01 = 0.f, a10 = 0.f, a11 = 0.f;
#pragma unroll 4
    for (int j = 0; j < kF; ++j) {
      const float al0 = sT[0][j][i];
      const float al1 = sT[1][j][i];
      const float2 e0 = *(const float2*)&el[0][j][dh];
      const float2 e1 = *(const float2*)&el[1][j][dh];
      a00 = fmaf(al0, e0.x, a00);
      a01 = fmaf(al0, e0.y, a01);
      a10 = fmaf(al1, e1.x, a10);
      a11 = fmaf(al1, e1.y, a11);
    }
    const float bs0 = bias[dh] + bias[kD + dh];
    const float bs1 = bias[dh + 1] + bias[kD + dh + 1];
    float* ob = out + b * (kD * kF) + i0 + i;
    ob[dh * kF] = 0.5f * (a00 + a10 + bs0);
    ob[(dh + 1) * kF] = 0.5f * (a01 + a11 + bs1);
  }
}

extern "C" void kernel_launch(void* const* d_in, const int* in_sizes, int n_in,
                              void* d_out, int out_size, void* d_ws,
                              size_t ws_size, hipStream_t stream) {
  (void)in_sizes; (void)n_in; (void)ws_size; (void)out_size;
  const float* x = (const float*)d_in[0];
  const float* Wl = (const float*)d_in[1];
  const float* Wr = (const float*)d_in[2];
  const float* attn_a = (const float*)d_in[3];
  const float* bias = (const float*)d_in[4];
  float* out = (float*)d_out;

  float* elw = (float*)d_ws;                  // [B][64][256]
  float* erw = elw + (size_t)kB * kF * kHD;   // [B][64][256]

  gat_proj<<<dim3(kB * 8), dim3(512), 0, stream>>>(x, Wl, Wr, elw, erw);
  gat_attn<<<dim3(kB * 8), dim3(512), 0, stream>>>(elw, erw, attn_a, bias, out);
}

// Round 4
// 24.403 us; speedup vs baseline: 1.3042x; 1.0604x over previous
//
#include <hip/hip_runtime.h>
#include <hip/hip_bf16.h>

// GATv2 dense complete-graph, B=32, W=128 (in-feat), F=64 (nodes), H=2, D=128.
// K1: el/er projection — x tile in LDS (1 b128/iter), W streamed from global.
// K2: per (b, i-tile of 8): scores + in-wave softmax (shfl) + register-blocked
//     aggregate + head-mean, each output written exactly once.

constexpr int kB = 32, kW = 128, kF = 64, kH = 2, kD = 128, kHD = 256;
constexpr float kNeg = 0.2f;

__device__ __forceinline__ float lrelu(float v) { return fmaxf(v, kNeg * v); }

// ---------------- K1: projection ----------------
// grid = B*8 (8 column-slices of 32), block = 512.
__global__ __launch_bounds__(512) void gat_proj(
    const float* __restrict__ x, const float* __restrict__ Wl,
    const float* __restrict__ Wr, float* __restrict__ elw,
    float* __restrict__ erw) {
  __shared__ float xw[kW][kF + 4];
  const int b = blockIdx.x >> 3;
  const int c0 = (blockIdx.x & 7) << 5;
  const int t = threadIdx.x;

  const float* xb = x + b * (kW * kF);
#pragma unroll
  for (int k = 0; k < 16; ++k) {
    const int idx = t + (k << 9);
    xw[idx >> 6][idx & 63] = xb[idx];  // xw[w][n] = x[b][w][n]
  }
  __syncthreads();

  const int c = c0 + (t & 31);
  const int n0 = (t >> 5) << 2;  // 4 rows per thread
  float accl[4] = {0.f, 0.f, 0.f, 0.f};
  float accr[4] = {0.f, 0.f, 0.f, 0.f};
  const float* wlp = Wl + c;
  const float* wrp = Wr + c;

#pragma unroll 8
  for (int w = 0; w < kW; ++w) {
    const float wl = wlp[w * kHD];   // global, L2-hit, VMEM pipe
    const float wr = wrp[w * kHD];
    const float4 xa = *(const float4*)&xw[w][n0];
    accl[0] = fmaf(xa.x, wl, accl[0]); accr[0] = fmaf(xa.x, wr, accr[0]);
    accl[1] = fmaf(xa.y, wl, accl[1]); accr[1] = fmaf(xa.y, wr, accr[1]);
    accl[2] = fmaf(xa.z, wl, accl[2]); accr[2] = fmaf(xa.z, wr, accr[2]);
    accl[3] = fmaf(xa.w, wl, accl[3]); accr[3] = fmaf(xa.w, wr, accr[3]);
  }

  const int base = (b * kF + n0) * kHD + c;
#pragma unroll
  for (int k = 0; k < 4; ++k) {
    elw[base + k * kHD] = accl[k];
    erw[base + k * kHD] = accr[k];
  }
}

// ---------------- K2: attention (both heads per block) ----------------
// grid = B*8 (i-tiles of 8), block = 512.
__global__ __launch_bounds__(512) void gat_attn(
    const float* __restrict__ elw, const float* __restrict__ erw,
    const float* __restrict__ attn_a, const float* __restrict__ bias,
    float* __restrict__ out) {
  __shared__ float el[kH][kF][kD + 4];     // 67.6 KB
  __shared__ float er[kH][8][kD + 4];      //  8.4 KB
  __shared__ float av[kH][kD];             //  1 KB
  __shared__ float sAT[kH][kF][8];         // alphas [h][j][i], 4 KB
  __shared__ float pbuf[4][kH][8][kD + 4]; // j-quarter partials, 33 KB

  const int b = blockIdx.x >> 3;
  const int i0 = (blockIdx.x & 7) << 3;
  const int t = threadIdx.x;

  // ---- stage: el (both heads, 64 src rows), er (8 dst rows), attn_a ----
  {
    const float* elb = elw + b * (kF * kHD);
#pragma unroll
    for (int k = 0; k < 8; ++k) {
      const int s = t + (k << 9);        // 0..4095 float4 slots
      const int h = s >> 11;
      const int n = (s >> 5) & 63;
      const int dv = (s & 31) << 2;
      *(float4*)&el[h][n][dv] = *(const float4*)&elb[n * kHD + h * kD + dv];
    }
    const float* erb = erw + (b * kF + i0) * kHD;
    {
      const int h = t >> 8;
      const int r = (t >> 5) & 7;
      const int dv = (t & 31) << 2;
      *(float4*)&er[h][r][dv] = *(const float4*)&erb[r * kHD + h * kD + dv];
    }
    if (t < kH * kD) av[t >> 7][t & 127] = attn_a[t];
  }
  __syncthreads();

  // ---- scores + in-wave softmax ----
  // thread = q(4b) | jh(1b) | i(3b) | h(1b): the 32 threads sharing (h,i)
  // are one aligned 32-lane group -> shfl softmax, no LDS round-trip.
  {
    const int q = t & 15;
    const int jh = (t >> 4) & 1;
    const int i = (t >> 5) & 7;
    const int h = t >> 8;
    const int j0 = q + (jh << 5);   // {0..15} u {32..47}
    const int j1 = j0 + 16;         // {16..31} u {48..63}
    float e0 = 0.f, e1 = 0.f;
#pragma unroll
    for (int dv = 0; dv < kD; dv += 4) {
      const float4 rv = *(const float4*)&er[h][i][dv];
      const float4 a4 = *(const float4*)&av[h][dv];
      const float4 p0 = *(const float4*)&el[h][j0][dv];
      const float4 p1 = *(const float4*)&el[h][j1][dv];
      e0 = fmaf(lrelu(p0.x + rv.x), a4.x, e0);
      e0 = fmaf(lrelu(p0.y + rv.y), a4.y, e0);
      e0 = fmaf(lrelu(p0.z + rv.z), a4.z, e0);
      e0 = fmaf(lrelu(p0.w + rv.w), a4.w, e0);
      e1 = fmaf(lrelu(p1.x + rv.x), a4.x, e1);
      e1 = fmaf(lrelu(p1.y + rv.y), a4.y, e1);
      e1 = fmaf(lrelu(p1.z + rv.z), a4.z, e1);
      e1 = fmaf(lrelu(p1.w + rv.w), a4.w, e1);
    }
    // softmax over the 32-lane (h,i) group; each lane holds 2 of 64 j's
    float m = fmaxf(e0, e1);
#pragma unroll
    for (int off = 1; off < 32; off <<= 1) m = fmaxf(m, __shfl_xor(m, off));
    const float x0 = __expf(e0 - m);
    const float x1 = __expf(e1 - m);
    float s = x0 + x1;
#pragma unroll
    for (int off = 1; off < 32; off <<= 1) s += __shfl_xor(s, off);
    const float inv = 1.f / s;
    sAT[h][j0][i] = x0 * inv;
    sAT[h][j1][i] = x1 * inv;
  }
  __syncthreads();

  // ---- aggregate: thread = dq(5b) | ip(1b) | jq(2b) | h(1b) ----
  // 4i x 4d register tile; per j: 1 b128 alpha (broadcast) + 1 b128 el.
  {
    const int dq = t & 31;          // d = dq*4 .. +3
    const int ip = (t >> 5) & 1;    // i = ip*4 .. +3
    const int jq = (t >> 6) & 3;    // 16 j's
    const int h = t >> 8;
    float acc[4][4] = {};
    const int jbase = jq << 4;
#pragma unroll
    for (int jj = 0; jj < 16; ++jj) {
      const int j = jbase + jj;
      const float4 al = *(const float4*)&sAT[h][j][ip << 2];
      const float4 ev = *(const float4*)&el[h][j][dq << 2];
      acc[0][0] = fmaf(al.x, ev.x, acc[0][0]);
      acc[0][1] = fmaf(al.x, ev.y, acc[0][1]);
      acc[0][2] = fmaf(al.x, ev.z, acc[0][2]);
      acc[0][3] = fmaf(al.x, ev.w, acc[0][3]);
      acc[1][0] = fmaf(al.y, ev.x, acc[1][0]);
      acc[1][1] = fmaf(al.y, ev.y, acc[1][1]);
      acc[1][2] = fmaf(al.y, ev.z, acc[1][2]);
      acc[1][3] = fmaf(al.y, ev.w, acc[1][3]);
      acc[2][0] = fmaf(al.z, ev.x, acc[2][0]);
      acc[2][1] = fmaf(al.z, ev.y, acc[2][1]);
      acc[2][2] = fmaf(al.z, ev.z, acc[2][2]);
      acc[2][3] = fmaf(al.z, ev.w, acc[2][3]);
      acc[3][0] = fmaf(al.w, ev.x, acc[3][0]);
      acc[3][1] = fmaf(al.w, ev.y, acc[3][1]);
      acc[3][2] = fmaf(al.w, ev.z, acc[3][2]);
      acc[3][3] = fmaf(al.w, ev.w, acc[3][3]);
    }
#pragma unroll
    for (int ii = 0; ii < 4; ++ii) {
      float4 v;
      v.x = acc[ii][0]; v.y = acc[ii][1]; v.z = acc[ii][2]; v.w = acc[ii][3];
      *(float4*)&pbuf[jq][h][(ip << 2) + ii][dq << 2] = v;
    }
  }
  __syncthreads();

  // ---- final: sum jq partials + heads, bias, mean, store ----
  {
    const int i = t & 7;
    const int d = (t >> 3) << 1;    // d-pair
    float o0 = 0.f, o1 = 0.f;
#pragma unroll
    for (int jq = 0; jq < 4; ++jq) {
#pragma unroll
      for (int h = 0; h < 2; ++h) {
        const float2 v = *(const float2*)&pbuf[jq][h][i][d];
        o0 += v.x;
        o1 += v.y;
      }
    }
    const float b0 = bias[d] + bias[kD + d];
    const float b1 = bias[d + 1] + bias[kD + d + 1];
    float* ob = out + b * (kD * kF) + i0 + i;
    ob[d * kF] = 0.5f * (o0 + b0);
    ob[(d + 1) * kF] = 0.5f * (o1 + b1);
  }
}

extern "C" void kernel_launch(void* const* d_in, const int* in_sizes, int n_in,
                              void* d_out, int out_size, void* d_ws,
                              size_t ws_size, hipStream_t stream) {
  (void)in_sizes; (void)n_in; (void)ws_size; (void)out_size;
  const float* x = (const float*)d_in[0];
  const float* Wl = (const float*)d_in[1];
  const float* Wr = (const float*)d_in[2];
  const float* attn_a = (const float*)d_in[3];
  const float* bias = (const float*)d_in[4];
  float* out = (float*)d_out;

  float* elw = (float*)d_ws;                  // [B][64][256]
  float* erw = elw + (size_t)kB * kF * kHD;   // [B][64][256]

  gat_proj<<<dim3(kB * 8), dim3(512), 0, stream>>>(x, Wl, Wr, elw, erw);
  gat_attn<<<dim3(kB * 8), dim3(512), 0, stream>>>(elw, erw, attn_a, bias, out);
}